// Round 15
// baseline (4227.798 us; speedup 1.0000x reference)
//
#include <hip/hip_runtime.h>
#include <hip/hip_bf16.h>
#include <math.h>

// ---------------------------------------------------------------------------
// BiLSTM-CRF, fp32 end-to-end (GEMMs via bf16x3-split MFMA, fp32 accumulate).
// Sizes: B=64 T=256 CHAR_E=256 POS_E=128 Hp=128, Hm=256, Dm=640, LBL=20.
// R15: main_rec 3-phase overlap WITHOUT R8's spill: ONE pinned array wv[40]
// (same 160-reg budget as proven R7), k-order permuted per thread:
// wv[0..31]=own-half k, wv[32..39]+19f4 LDS+5f4 L2-tail=partner-half k.
// Step: gates+store(h in flight) -> barrier -> own-half matvec + gmain
// prefetch UNDER the L3 round trip -> poll -> barrier -> partner matvec.
// GEMM/gather/pos_rec = R14 (pre-split bf16x3 MFMA, proven absmax 0).
// ---------------------------------------------------------------------------

#define Bsz 64
#define Tsz 256
#define NROW 16384        // B*T

__device__ __forceinline__ float sigm(float x) { return 1.f / (1.f + expf(-x)); }

#define PIN4(v) asm volatile("" : "+v"((v).x), "+v"((v).y), "+v"((v).z), "+v"((v).w))

typedef float f32x4 __attribute__((ext_vector_type(4)));
typedef short short8 __attribute__((ext_vector_type(8)));
typedef unsigned short u16;
typedef u16 u16x8 __attribute__((ext_vector_type(8)));

// fp32 -> (bf16 hi, bf16 lo), RNE both. Finite inputs only. (R13-proven)
__device__ __forceinline__ void bf16split(float f, u16& h, u16& l) {
  unsigned u = __float_as_uint(f);
  unsigned hh = (u + 0x7FFFu + ((u >> 16) & 1u)) >> 16;
  h = (u16)hh;
  float hf = __uint_as_float(hh << 16);
  unsigned v = __float_as_uint(f - hf);
  l = (u16)((v + 0x7FFFu + ((v >> 16) & 1u)) >> 16);
}

// --------------------- weight pre-split (4 matrices, once) -------------------
__global__ __launch_bounds__(256) void wsplit4(
    const float* __restrict__ s0, u16* __restrict__ h0, u16* __restrict__ l0, int n0,
    const float* __restrict__ s1, u16* __restrict__ h1, u16* __restrict__ l1, int n1,
    const float* __restrict__ s2, u16* __restrict__ h2, u16* __restrict__ l2, int n2,
    const float* __restrict__ s3, u16* __restrict__ h3, u16* __restrict__ l3, int n3) {
  int i = (blockIdx.x * 256 + threadIdx.x) * 4;
  const float* s; u16 *h, *l;
  if (i < n0) { s = s0; h = h0; l = l0; }
  else if ((i -= n0) < n1) { s = s1; h = h1; l = l1; }
  else if ((i -= n1) < n2) { s = s2; h = h2; l = l2; }
  else if ((i -= n2) < n3) { s = s3; h = h3; l = l3; }
  else return;
  float4 v = *(const float4*)&s[i];
  ushort4 hh, ll;
  bf16split(v.x, hh.x, ll.x); bf16split(v.y, hh.y, ll.y);
  bf16split(v.z, hh.z, ll.z); bf16split(v.w, hh.w, ll.w);
  *(ushort4*)&h[i] = hh; *(ushort4*)&l[i] = ll;
}

// ---------------- gather: embeddings -> pre-split bf16 hi/lo -----------------
__global__ __launch_bounds__(256) void gather_kernel(
    const int* __restrict__ ci, const int* __restrict__ pi, const int* __restrict__ ti,
    const float* __restrict__ ce, const float* __restrict__ pe, const float* __restrict__ te,
    u16* __restrict__ tbh, u16* __restrict__ tbl,
    u16* __restrict__ emh, u16* __restrict__ eml) {
  int gid = blockIdx.x * 256 + threadIdx.x;     // NROW*128 threads
  int m = gid >> 7, s = gid & 127;
  float4 v; size_t off; u16 *ph, *pl;
  if (s < 32) {
    v = ((const float4*)&te[(size_t)ti[m] * 128])[s];
    off = (size_t)m * 128 + s * 4; ph = tbh; pl = tbl;
  } else if (s < 96) {
    v = ((const float4*)&ce[(size_t)ci[m] * 256])[s - 32];
    off = (size_t)m * 640 + (s - 32) * 4; ph = emh; pl = eml;
  } else {
    v = ((const float4*)&pe[(size_t)pi[m] * 128])[s - 96];
    off = (size_t)m * 640 + 256 + (s - 96) * 4; ph = emh; pl = eml;
  }
  ushort4 h, l;
  bf16split(v.x, h.x, l.x); bf16split(v.y, h.y, l.y);
  bf16split(v.z, h.z, l.z); bf16split(v.w, h.w, l.w);
  *(ushort4*)&ph[off] = h; *(ushort4*)&pl[off] = l;
}

// ------- MFMA GEMM: C[m, n0+c] = A[m,:].W[n0+c,:] + bias   (pre-split) -------
#define GTM 512
#define GTN 128
__global__ __launch_bounds__(512) void gemm_bf16x3(
    const u16* __restrict__ Ah, const u16* __restrict__ Al,
    const u16* __restrict__ Wh, const u16* __restrict__ Wl,
    const float* __restrict__ biasF, const float* __restrict__ biasB,
    float* __restrict__ C, int ldc, int K, int NhB) {
  extern __shared__ u16 us[];
  u16* As_h = us;                        // [512][40]
  u16* As_l = us + 512 * 40;
  u16* Ws_h = us + 2 * 512 * 40;         // [128][40]
  u16* Ws_l = us + 2 * 512 * 40 + 128 * 40;
  const int tid = threadIdx.x;
  const int lane = tid & 63, wv = tid >> 6;
  const int l15 = lane & 15, l8 = (lane >> 4) * 8, l4 = lane >> 4;
  const int m0 = blockIdx.y * GTM;
  const int n0 = blockIdx.x * GTN;       // col into C / row into concat W
  const u16* WhS = Wh + (size_t)n0 * K;
  const u16* WlS = Wl + (size_t)n0 * K;
  const float* bias = (blockIdx.x < (unsigned)NhB) ? (biasF + n0)
                                                   : (biasB + (n0 - NhB * GTN));
  const int arow = tid >> 2, aq = (tid & 3) * 8;   // staging coords

  u16x8 rA[4][2], rW[2];
#define LOAD_TILES(k0)                                                         \
  {                                                                            \
    _Pragma("unroll")                                                          \
    for (int r = 0; r < 4; ++r) {                                              \
      int row = arow + r * 128;                                                \
      rA[r][0] = *(const u16x8*)&Ah[(size_t)(m0 + row) * K + (k0) + aq];       \
      rA[r][1] = *(const u16x8*)&Al[(size_t)(m0 + row) * K + (k0) + aq];       \
    }                                                                          \
    rW[0] = *(const u16x8*)&WhS[(size_t)arow * K + (k0) + aq];                 \
    rW[1] = *(const u16x8*)&WlS[(size_t)arow * K + (k0) + aq];                 \
  }

  f32x4 acc[4][8] = {};
  LOAD_TILES(0);
  for (int k0 = 0; k0 < K; k0 += 32) {
#pragma unroll
    for (int r = 0; r < 4; ++r) {
      int row = arow + r * 128;
      *(u16x8*)&As_h[row * 40 + aq] = rA[r][0];
      *(u16x8*)&As_l[row * 40 + aq] = rA[r][1];
    }
    if (arow < 128) {
      *(u16x8*)&Ws_h[arow * 40 + aq] = rW[0];
      *(u16x8*)&Ws_l[arow * 40 + aq] = rW[1];
    }
    __syncthreads();
    if (k0 + 32 < K) LOAD_TILES(k0 + 32);
    short8 aH[4], aL[4];
#pragma unroll
    for (int fr = 0; fr < 4; ++fr) {
      aH[fr] = *(const short8*)&As_h[(wv * 64 + fr * 16 + l15) * 40 + l8];
      aL[fr] = *(const short8*)&As_l[(wv * 64 + fr * 16 + l15) * 40 + l8];
    }
#pragma unroll
    for (int cf = 0; cf < 8; ++cf) {
      short8 bH = *(const short8*)&Ws_h[(cf * 16 + l15) * 40 + l8];
      short8 bL = *(const short8*)&Ws_l[(cf * 16 + l15) * 40 + l8];
#pragma unroll
      for (int fr = 0; fr < 4; ++fr) {
        acc[fr][cf] = __builtin_amdgcn_mfma_f32_16x16x32_bf16(aH[fr], bH, acc[fr][cf], 0, 0, 0);
        acc[fr][cf] = __builtin_amdgcn_mfma_f32_16x16x32_bf16(aH[fr], bL, acc[fr][cf], 0, 0, 0);
        acc[fr][cf] = __builtin_amdgcn_mfma_f32_16x16x32_bf16(aL[fr], bH, acc[fr][cf], 0, 0, 0);
      }
    }
    __syncthreads();
  }
  // epilogue: D row=(lane>>4)*4+q, col=lane&15 (m89/m91 mapping)
#pragma unroll
  for (int fr = 0; fr < 4; ++fr)
#pragma unroll
    for (int cf = 0; cf < 8; ++cf) {
      int col = cf * 16 + l15;
      float bs = bias[col];
#pragma unroll
      for (int q = 0; q < 4; ++q) {
        size_t row = m0 + wv * 64 + fr * 16 + l4 * 4 + q;
        C[row * ldc + n0 + col] = acc[fr][cf][q] + bs;
      }
    }
#undef LOAD_TILES
}

// --------------------------- pos BiLSTM recurrence ---------------------------
// R7-exact core; outputs pre-split bf16 hi/lo (R14-proven).
__global__ __launch_bounds__(512, 2) void pos_rec(
    const int* __restrict__ lengths, const float* __restrict__ gpos,
    const float* __restrict__ Wf, const float* __restrict__ Wb,
    u16* __restrict__ emh, u16* __restrict__ eml) {
  const int blk = blockIdx.x;
  const int b = blk >> 1, dir = blk & 1;
  const int j = threadIdx.x;
  const int gc = j >> 7;
  const int len = lengths[b];
  const float* W = dir ? Wb : Wf;
  __shared__ __align__(16) float h[128];
  __shared__ float gbuf[512];
  float4 w4[32];
#pragma unroll
  for (int i = 0; i < 32; ++i) w4[i] = *(const float4*)&W[(size_t)j * 128 + i * 4];
#pragma unroll
  for (int i = 0; i < 32; ++i) PIN4(w4[i]);
  float c = 0.f;
  if (j < 128) h[j] = 0.f;
  __syncthreads();
  int idx0 = dir ? (len - 1) : 0;
  float gcur = gpos[((size_t)(b * Tsz + idx0)) * 1024 + dir * 512 + j];
  for (int t = 0; t < len; ++t) {
    const int idx = dir ? (len - 1 - t) : t;
    const int tn = (t + 1 < len) ? t + 1 : t;
    const int idxn = dir ? (len - 1 - tn) : tn;
    float gnext = gpos[((size_t)(b * Tsz + idxn)) * 1024 + dir * 512 + j];
    float acc = gcur;
    const float4* h4 = (const float4*)h;
#pragma unroll
    for (int i = 0; i < 32; ++i) {
      float4 hh = h4[i];
      acc = fmaf(hh.x, w4[i].x, acc); acc = fmaf(hh.y, w4[i].y, acc);
      acc = fmaf(hh.z, w4[i].z, acc); acc = fmaf(hh.w, w4[i].w, acc);
    }
    gbuf[j] = (gc == 2) ? tanhf(acc) : sigm(acc);
    __syncthreads();
    if (j < 128) {
      float si = gbuf[j], sf = gbuf[128 + j], tg = gbuf[256 + j], so = gbuf[384 + j];
      c = sf * c + si * tg;
      float hn = so * tanhf(c);
      h[j] = hn;
      u16 hh2, hl2; bf16split(hn, hh2, hl2);
      size_t eo = ((size_t)(b * Tsz + idx)) * 640 + 384 + dir * 128 + j;
      emh[eo] = hh2; eml[eo] = hl2;
    }
    __syncthreads();
    gcur = gnext;
  }
}

// --------------------------- main BiLSTM recurrence --------------------------
// 256 blocks: blk = b*4 + dir*2 + half; partner = blk^1.
// 512 threads = 512 gate rows of this half's 128 h-units.
// Weights/thread PERMUTED: wv[0..31] = own-half k (32 f4), wv[32..39] =
// partner k [0,32), wl 19 f4 = partner k [32,108), tail 5 f4 (L2) = [108,128).
// Step: j<128 gates(t)->h->store (flight starts) -> barrier A ->
// ALL: own-half matvec + gmain(t+2) prefetch; j<128 poll -> barrier B ->
// ALL: partner-half matvec -> act -> barrier C.
#define MR_OWN 32
#define MR_PV  8
#define MR_PL  19
#define MR_PT  5
#define HX_STRIDE 256      // ull per block (2 parity slots x 128)
__global__ __launch_bounds__(512, 2) void main_rec(
    const int* __restrict__ lengths, const float* __restrict__ gmain,
    const float* __restrict__ Wf, const float* __restrict__ Wb,
    float* __restrict__ lstm_out, unsigned long long* __restrict__ hx) {
  extern __shared__ float smem[];
  float4* wl   = (float4*)smem;                    // [MR_PL*512] float4
  float* hown  = smem + MR_PL * 512 * 4;           // 128
  float* hpart = hown + 128;                       // 128
  float* gbuf  = hpart + 128;                      // 512

  const int blk = blockIdx.x;
  const int b = blk >> 2, dir = (blk >> 1) & 1, half = blk & 1;
  const int j = threadIdx.x;
  const int gc = j >> 7, ul = j & 127;
  const int r = gc * 256 + half * 128 + ul;        // gate row in [0,1024)
  const int len = lengths[b];
  const float* Wr = (dir ? Wb : Wf) + (size_t)r * 256;
  const int ob = half * 128, pb = (half ^ 1) * 128;

  float4 wv[MR_OWN + MR_PV];
#pragma unroll
  for (int i = 0; i < MR_OWN; ++i) wv[i] = *(const float4*)&Wr[ob + i * 4];
#pragma unroll
  for (int i = 0; i < MR_PV; ++i) wv[MR_OWN + i] = *(const float4*)&Wr[pb + i * 4];
#pragma unroll
  for (int i = 0; i < MR_OWN + MR_PV; ++i) PIN4(wv[i]);
#pragma unroll
  for (int i = 0; i < MR_PL; ++i) wl[i * 512 + j] = *(const float4*)&Wr[pb + 32 + i * 4];

  unsigned long long* selfD = hx + (size_t)blk * HX_STRIDE;
  unsigned long long* partD = hx + (size_t)(blk ^ 1) * HX_STRIDE;
  const int obase = dir * 256 + half * 128;

  // prologue: gates(0) = act(gmain(0)) (h=c=0); prefetch gmain(1)
  const int idx0 = dir ? (len - 1) : 0;
  float g0 = gmain[((size_t)(b * Tsz + idx0)) * 2048 + dir * 1024 + r];
  gbuf[j] = (gc == 2) ? tanhf(g0) : sigm(g0);
  const int idx1 = dir ? (len - 2) : 1;            // len >= 128 always
  float gnext = gmain[((size_t)(b * Tsz + idx1)) * 2048 + dir * 1024 + r];
  float c = 0.f;
  __syncthreads();

  for (int t = 0; t < len; ++t) {
    const int idx = dir ? (len - 1 - t) : t;
    // ---- phase 1: j<128: gates(t)->h(t); exchange store FIRST ----
    if (j < 128) {
      float si = gbuf[ul], sf = gbuf[128 + ul], tg = gbuf[256 + ul], so = gbuf[384 + ul];
      c = sf * c + si * tg;
      float hn = so * tanhf(c);
      if (t + 1 < len) {
        union { float f; unsigned u; } cv; cv.f = hn;
        unsigned long long pk =
            ((unsigned long long)(unsigned)(t + 1) << 32) | (unsigned long long)cv.u;
        __hip_atomic_store(&selfD[(t & 1) * 128 + ul], pk,
                           __ATOMIC_RELAXED, __HIP_MEMORY_SCOPE_AGENT);
      }
      lstm_out[((size_t)(b * Tsz + idx)) * 512 + obase + ul] = hn;
      hown[ul] = hn;
    }
    if (t + 1 == len) break;
    __syncthreads();   // A: hown(t) ready; partner h in flight

    // ---- phase 2: ALL: own-half matvec; prefetch gmain(t+2) ----
    float acc = gnext;
    {
      const float4* ho = (const float4*)hown;
#pragma unroll
      for (int i = 0; i < MR_OWN; ++i) {
        float4 hh = ho[i], w = wv[i];
        acc = fmaf(hh.x, w.x, acc); acc = fmaf(hh.y, w.y, acc);
        acc = fmaf(hh.z, w.z, acc); acc = fmaf(hh.w, w.w, acc);
      }
    }
    const int t2 = (t + 2 < len) ? t + 2 : len - 1;
    const int idx2 = dir ? (len - 1 - t2) : t2;
    float gnn = gmain[((size_t)(b * Tsz + idx2)) * 2048 + dir * 1024 + r];

    // ---- j<128: poll partner h(t) (store ~0.6us in flight already) ----
    if (j < 128) {
      unsigned long long pv; int guard = 0;
      for (;;) {
        pv = __hip_atomic_load(&partD[(t & 1) * 128 + ul],
                               __ATOMIC_RELAXED, __HIP_MEMORY_SCOPE_AGENT);
        if ((unsigned)(pv >> 32) == (unsigned)(t + 1)) break;
        if (++guard > (1 << 22)) break;   // watchdog
        __builtin_amdgcn_s_sleep(1);
      }
      union { unsigned u; float f; } hv; hv.u = (unsigned)(pv & 0xffffffffull);
      hpart[ul] = hv.f;
    }
    __syncthreads();   // B: hpart(t) ready

    // ---- phase 3: ALL: partner-half matvec; act -> gbuf(t+1) ----
    {
      const float4* hp = (const float4*)hpart;
#pragma unroll
      for (int i = 0; i < MR_PV; ++i) {
        float4 hh = hp[i], w = wv[MR_OWN + i];
        acc = fmaf(hh.x, w.x, acc); acc = fmaf(hh.y, w.y, acc);
        acc = fmaf(hh.z, w.z, acc); acc = fmaf(hh.w, w.w, acc);
      }
#pragma unroll
      for (int i = 0; i < MR_PL; ++i) {
        float4 hh = hp[MR_PV + i], w = wl[i * 512 + j];
        acc = fmaf(hh.x, w.x, acc); acc = fmaf(hh.y, w.y, acc);
        acc = fmaf(hh.z, w.z, acc); acc = fmaf(hh.w, w.w, acc);
      }
#pragma unroll
      for (int i = 0; i < MR_PT; ++i) {
        float4 hh = hp[MR_PV + MR_PL + i];
        float4 w = *(const float4*)&Wr[pb + 108 + i * 4];
        acc = fmaf(hh.x, w.x, acc); acc = fmaf(hh.y, w.y, acc);
        acc = fmaf(hh.z, w.z, acc); acc = fmaf(hh.w, w.w, acc);
      }
    }
    gbuf[j] = (gc == 2) ? tanhf(acc) : sigm(acc);
    __syncthreads();   // C: gbuf(t+1) ready
    gnext = gnn;
  }
}

// ------------------------------- emit GEMM -----------------------------------
__global__ __launch_bounds__(256) void emit_kernel(
    const float* __restrict__ lstm_out, const float* __restrict__ Wout,
    const float* __restrict__ bout, float* __restrict__ emit) {
  int gid = blockIdx.x * 256 + threadIdx.x;      // NROW*32 threads
  int m = gid >> 5, j = gid & 31;
  if (j >= 20) return;
  const float4* xr = (const float4*)&lstm_out[(size_t)m * 512];
  const float4* wr = (const float4*)&Wout[(size_t)j * 512];
  float acc = bout[j];
#pragma unroll 8
  for (int i = 0; i < 128; ++i) {
    float4 x = xr[i], w = wr[i];
    acc += x.x * w.x + x.y * w.y + x.z * w.z + x.w * w.w;
  }
  emit[(size_t)m * 20 + j] = acc;
}

// ------------------------------- Viterbi -------------------------------------
__global__ __launch_bounds__(64) void viterbi_kernel(
    const int* __restrict__ lengths, const float* __restrict__ emit,
    const float* __restrict__ trans, int* __restrict__ out) {
  const int b = blockIdx.x, j = threadIdx.x;
  const int len = lengths[b];
  __shared__ float tr[400];
  __shared__ float alpha[20];
  __shared__ float fin[20];
  __shared__ unsigned char bp[256][20];
  for (int i = j; i < 400; i += 64) tr[i] = trans[i];
  __syncthreads();
  if (j < 20) alpha[j] = tr[18 * 20 + j] + emit[(size_t)(b * Tsz) * 20 + j];
  __syncthreads();
  for (int t = 1; t < len; ++t) {
    float best = 0.f; int bi = 0;
    if (j < 20) {
      best = alpha[0] + tr[j];
#pragma unroll
      for (int i = 1; i < 20; ++i) {
        float s = alpha[i] + tr[i * 20 + j];
        if (s > best) { best = s; bi = i; }
      }
      best += emit[((size_t)(b * Tsz + t)) * 20 + j];
    }
    __syncthreads();
    if (j < 20) { alpha[j] = best; bp[t][j] = (unsigned char)bi; }
    __syncthreads();
  }
  if (j < 20) fin[j] = alpha[j] + tr[j * 20 + 19];
  __syncthreads();
  if (j == 0) {
    float best = fin[0]; int tag = 0;
    for (int i = 1; i < 20; ++i) if (fin[i] > best) { best = fin[i]; tag = i; }
    out[b * Tsz + len - 1] = tag;
    for (int t = len - 1; t >= 1; --t) { tag = bp[t][tag]; out[b * Tsz + t - 1] = tag; }
  }
  for (int t = len + j; t < Tsz; t += 64) out[b * Tsz + t] = 0;
}

// ------------------------------- launcher ------------------------------------
extern "C" void kernel_launch(void* const* d_in, const int* in_sizes, int n_in,
                              void* d_out, int out_size, void* d_ws, size_t ws_size,
                              hipStream_t stream) {
  const int*   char_in = (const int*)d_in[0];
  const int*   pos_in  = (const int*)d_in[1];
  const int*   tag_in  = (const int*)d_in[2];
  const int*   lengths = (const int*)d_in[3];
  // d_in[4] = mask: recomputed from lengths, unused.
  const float* ce      = (const float*)d_in[5];
  const float* pe      = (const float*)d_in[6];
  const float* te      = (const float*)d_in[7];
  const float* pWih_f  = (const float*)d_in[8];
  const float* pWhh_f  = (const float*)d_in[9];
  const float* pb_f    = (const float*)d_in[10];
  const float* pWih_b  = (const float*)d_in[11];
  const float* pWhh_b  = (const float*)d_in[12];
  const float* pb_b    = (const float*)d_in[13];
  const float* mWih_f  = (const float*)d_in[14];
  const float* mWhh_f  = (const float*)d_in[15];
  const float* mb_f    = (const float*)d_in[16];
  const float* mWih_b  = (const float*)d_in[17];
  const float* mWhh_b  = (const float*)d_in[18];
  const float* mb_b    = (const float*)d_in[19];
  const float* W_out   = (const float*)d_in[20];
  const float* b_out   = (const float*)d_in[21];
  const float* trans   = (const float*)d_in[22];

  float* ws = (float*)d_ws;
  // ---- layout (float offsets), overlays verified by stage liveness ----
  const size_t WPH     = 0;                        //  65536 f (131072 u16: pos f|b)
  const size_t WPL     = 65536;                    //  65536
  const size_t WMH     = 131072;                   // 655360 f (main f|b)
  const size_t WML     = 786432;                   // 655360
  const size_t EMH     = 1441792;                  // 5242880 f (16384*640 u16)
  const size_t EML     = 6684672;                  // 5242880
  const size_t TBH     = 11927552;                 // 1048576 f (16384*128 u16)
  const size_t TBL     = 12976128;                 // 1048576
  const size_t GPOS    = 14024704;                 // 16777216 f
  const size_t GMAIN   = 11927552;                 // 33554432 f (overlays TB+GPOS+fresh)
  const size_t LSTMOUT = 1441792;                  // 8388608 f (overlays EMH/EML, dead)
  const size_t EMIT    = 9830400;                  // 327680 f (tail of EM region)
  const size_t HX      = 45481984;                 // 131072 f (fresh, after GMAIN)

  // clear exchange region (stale tags must never match)
  hipMemsetAsync(ws + HX, 0, HX_STRIDE * 256 * sizeof(unsigned long long), stream);

  // weight pre-split (once): pos f, pos b, main f, main b
  wsplit4<<<1408, 256, 0, stream>>>(
      pWih_f, (u16*)(ws + WPH),          (u16*)(ws + WPL),          65536,
      pWih_b, (u16*)(ws + WPH) + 65536,  (u16*)(ws + WPL) + 65536,  65536,
      mWih_f, (u16*)(ws + WMH),          (u16*)(ws + WML),          655360,
      mWih_b, (u16*)(ws + WMH) + 655360, (u16*)(ws + WML) + 655360, 655360);

  gather_kernel<<<8192, 256, 0, stream>>>(char_in, pos_in, tag_in, ce, pe, te,
                                          (u16*)(ws + TBH), (u16*)(ws + TBL),
                                          (u16*)(ws + EMH), (u16*)(ws + EML));

  const int GSMEM = (2 * 512 * 40 + 2 * 128 * 40) * 2;   // 102400 B
  hipFuncSetAttribute((const void*)gemm_bf16x3,
                      hipFuncAttributeMaxDynamicSharedMemorySize, GSMEM);

  // pos input GEMM (f+b merged): [16384,128] x [1024,128]^T -> GPOS ldc 1024
  gemm_bf16x3<<<dim3(8, 32), 512, GSMEM, stream>>>(
      (u16*)(ws + TBH), (u16*)(ws + TBL),
      (u16*)(ws + WPH), (u16*)(ws + WPL),
      pb_f, pb_b, ws + GPOS, 1024, 128, 4);

  pos_rec<<<128, 512, 0, stream>>>(lengths, ws + GPOS, pWhh_f, pWhh_b,
                                   (u16*)(ws + EMH), (u16*)(ws + EML));

  // main input GEMM (f+b merged): [16384,640] x [2048,640]^T -> GMAIN ldc 2048
  gemm_bf16x3<<<dim3(16, 32), 512, GSMEM, stream>>>(
      (u16*)(ws + EMH), (u16*)(ws + EML),
      (u16*)(ws + WMH), (u16*)(ws + WML),
      mb_f, mb_b, ws + GMAIN, 2048, 640, 8);

  // LDS: 19*512*16 (weights) + 128*4 + 128*4 + 512*4 = 158720 B (<= 160 KiB)
  const int SMEM = MR_PL * 512 * 16 + 128 * 4 + 128 * 4 + 512 * 4;
  hipFuncSetAttribute((const void*)main_rec,
                      hipFuncAttributeMaxDynamicSharedMemorySize, SMEM);
  main_rec<<<256, 512, SMEM, stream>>>(lengths, ws + GMAIN, mWhh_f, mWhh_b,
                                       ws + LSTMOUT, (unsigned long long*)(ws + HX));

  emit_kernel<<<2048, 256, 0, stream>>>(ws + LSTMOUT, W_out, b_out, ws + EMIT);

  viterbi_kernel<<<64, 64, 0, stream>>>(lengths, ws + EMIT, trans, (int*)d_out);
}

// Round 16
// 1329.411 us; speedup vs baseline: 3.1802x; 3.1802x over previous
//
#include <hip/hip_runtime.h>
#include <hip/hip_bf16.h>
#include <math.h>

// ---------------------------------------------------------------------------
// BiLSTM-CRF, fp32 end-to-end (GEMMs via bf16x3-split MFMA, fp32 accumulate).
// Sizes: B=64 T=256 CHAR_E=256 POS_E=128 Hp=128, Hm=256, Dm=640, LBL=20.
// R16: R14-exact compute (best passing, 1266us) + low-risk overhead cuts:
// (1) prep kernel fuses wsplit4 + gather + HX-clear (-2 launches);
// (2) main_rec poll = hard spin (no s_sleep);
// (3) HX moved to low ws region (R11's 642us-population layout).
// main_rec structural floor established R2-R15: step = compute 0.7us +
// irreducible fabric exchange ~1.7us; sc0/same-L2 paths failed 3 probe
// designs; phase-split overlap spills (2/2); 1-block chain impossible
// (1MB weights > 512KB regfile).
// ---------------------------------------------------------------------------

#define Bsz 64
#define Tsz 256
#define NROW 16384        // B*T

__device__ __forceinline__ float sigm(float x) { return 1.f / (1.f + expf(-x)); }

#define PIN4(v) asm volatile("" : "+v"((v).x), "+v"((v).y), "+v"((v).z), "+v"((v).w))

typedef float f32x4 __attribute__((ext_vector_type(4)));
typedef short short8 __attribute__((ext_vector_type(8)));
typedef unsigned short u16;
typedef u16 u16x8 __attribute__((ext_vector_type(8)));

// fp32 -> (bf16 hi, bf16 lo), RNE both. Finite inputs only. (R13-proven)
__device__ __forceinline__ void bf16split(float f, u16& h, u16& l) {
  unsigned u = __float_as_uint(f);
  unsigned hh = (u + 0x7FFFu + ((u >> 16) & 1u)) >> 16;
  h = (u16)hh;
  float hf = __uint_as_float(hh << 16);
  unsigned v = __float_as_uint(f - hf);
  l = (u16)((v + 0x7FFFu + ((v >> 16) & 1u)) >> 16);
}

// ------------- prep: gather + weight pre-split + HX clear (fused) ------------
// blocks [0,8192): gather; [8192,9600): wsplit; [9600,9664): HX clear.
__global__ __launch_bounds__(256) void prep_kernel(
    const int* __restrict__ ci, const int* __restrict__ pi, const int* __restrict__ ti,
    const float* __restrict__ ce, const float* __restrict__ pe, const float* __restrict__ te,
    u16* __restrict__ tbh, u16* __restrict__ tbl,
    u16* __restrict__ emh, u16* __restrict__ eml,
    const float* __restrict__ s0, u16* __restrict__ h0, u16* __restrict__ l0, int n0,
    const float* __restrict__ s1, u16* __restrict__ h1, u16* __restrict__ l1, int n1,
    const float* __restrict__ s2, u16* __restrict__ h2, u16* __restrict__ l2, int n2,
    const float* __restrict__ s3, u16* __restrict__ h3, u16* __restrict__ l3, int n3,
    unsigned long long* __restrict__ hxClr) {
  const int bid = blockIdx.x;
  if (bid < 8192) {
    // ---- gather: embeddings -> pre-split bf16 hi/lo ----
    int gid = bid * 256 + threadIdx.x;          // NROW*128 threads
    int m = gid >> 7, s = gid & 127;
    float4 v; size_t off; u16 *ph, *pl;
    if (s < 32) {
      v = ((const float4*)&te[(size_t)ti[m] * 128])[s];
      off = (size_t)m * 128 + s * 4; ph = tbh; pl = tbl;
    } else if (s < 96) {
      v = ((const float4*)&ce[(size_t)ci[m] * 256])[s - 32];
      off = (size_t)m * 640 + (s - 32) * 4; ph = emh; pl = eml;
    } else {
      v = ((const float4*)&pe[(size_t)pi[m] * 128])[s - 96];
      off = (size_t)m * 640 + 256 + (s - 96) * 4; ph = emh; pl = eml;
    }
    ushort4 h, l;
    bf16split(v.x, h.x, l.x); bf16split(v.y, h.y, l.y);
    bf16split(v.z, h.z, l.z); bf16split(v.w, h.w, l.w);
    *(ushort4*)&ph[off] = h; *(ushort4*)&pl[off] = l;
  } else if (bid < 9600) {
    // ---- weight pre-split (R14 wsplit4 logic) ----
    int i = ((bid - 8192) * 256 + threadIdx.x) * 4;
    const float* s; u16 *h, *l;
    if (i < n0) { s = s0; h = h0; l = l0; }
    else if ((i -= n0) < n1) { s = s1; h = h1; l = l1; }
    else if ((i -= n1) < n2) { s = s2; h = h2; l = l2; }
    else if ((i -= n2) < n3) { s = s3; h = h3; l = l3; }
    else return;
    float4 v = *(const float4*)&s[i];
    ushort4 hh, ll;
    bf16split(v.x, hh.x, ll.x); bf16split(v.y, hh.y, ll.y);
    bf16split(v.z, hh.z, ll.z); bf16split(v.w, hh.w, ll.w);
    *(ushort4*)&h[i] = hh; *(ushort4*)&l[i] = ll;
  } else {
    // ---- HX clear: 65536 ull, 64 blocks x 256 thr x 4 ull ----
    size_t base = ((size_t)(bid - 9600) * 256 + threadIdx.x) * 4;
#pragma unroll
    for (int q = 0; q < 4; ++q) hxClr[base + q] = 0ull;
  }
}

// ------- MFMA GEMM: C[m, n0+c] = A[m,:].W[n0+c,:] + bias   (pre-split) -------
// R14-exact. Tile 512x128, 512 thr = 8 waves; wave: 4 rowfrags x 8 colfrags.
// bf16x3: acc += Ah.Wh + Ah.Wl + Al.Wh per 32-k step.
#define GTM 512
#define GTN 128
__global__ __launch_bounds__(512) void gemm_bf16x3(
    const u16* __restrict__ Ah, const u16* __restrict__ Al,
    const u16* __restrict__ Wh, const u16* __restrict__ Wl,
    const float* __restrict__ biasF, const float* __restrict__ biasB,
    float* __restrict__ C, int ldc, int K, int NhB) {
  extern __shared__ u16 us[];
  u16* As_h = us;                        // [512][40]
  u16* As_l = us + 512 * 40;
  u16* Ws_h = us + 2 * 512 * 40;         // [128][40]
  u16* Ws_l = us + 2 * 512 * 40 + 128 * 40;
  const int tid = threadIdx.x;
  const int lane = tid & 63, wv = tid >> 6;
  const int l15 = lane & 15, l8 = (lane >> 4) * 8, l4 = lane >> 4;
  const int m0 = blockIdx.y * GTM;
  const int n0 = blockIdx.x * GTN;       // col into C / row into concat W
  const u16* WhS = Wh + (size_t)n0 * K;
  const u16* WlS = Wl + (size_t)n0 * K;
  const float* bias = (blockIdx.x < (unsigned)NhB) ? (biasF + n0)
                                                   : (biasB + (n0 - NhB * GTN));
  const int arow = tid >> 2, aq = (tid & 3) * 8;   // staging coords

  u16x8 rA[4][2], rW[2];
#define LOAD_TILES(k0)                                                         \
  {                                                                            \
    _Pragma("unroll")                                                          \
    for (int r = 0; r < 4; ++r) {                                              \
      int row = arow + r * 128;                                                \
      rA[r][0] = *(const u16x8*)&Ah[(size_t)(m0 + row) * K + (k0) + aq];       \
      rA[r][1] = *(const u16x8*)&Al[(size_t)(m0 + row) * K + (k0) + aq];       \
    }                                                                          \
    rW[0] = *(const u16x8*)&WhS[(size_t)arow * K + (k0) + aq];                 \
    rW[1] = *(const u16x8*)&WlS[(size_t)arow * K + (k0) + aq];                 \
  }

  f32x4 acc[4][8] = {};
  LOAD_TILES(0);
  for (int k0 = 0; k0 < K; k0 += 32) {
#pragma unroll
    for (int r = 0; r < 4; ++r) {
      int row = arow + r * 128;
      *(u16x8*)&As_h[row * 40 + aq] = rA[r][0];
      *(u16x8*)&As_l[row * 40 + aq] = rA[r][1];
    }
    if (arow < 128) {
      *(u16x8*)&Ws_h[arow * 40 + aq] = rW[0];
      *(u16x8*)&Ws_l[arow * 40 + aq] = rW[1];
    }
    __syncthreads();
    if (k0 + 32 < K) LOAD_TILES(k0 + 32);
    short8 aH[4], aL[4];
#pragma unroll
    for (int fr = 0; fr < 4; ++fr) {
      aH[fr] = *(const short8*)&As_h[(wv * 64 + fr * 16 + l15) * 40 + l8];
      aL[fr] = *(const short8*)&As_l[(wv * 64 + fr * 16 + l15) * 40 + l8];
    }
#pragma unroll
    for (int cf = 0; cf < 8; ++cf) {
      short8 bH = *(const short8*)&Ws_h[(cf * 16 + l15) * 40 + l8];
      short8 bL = *(const short8*)&Ws_l[(cf * 16 + l15) * 40 + l8];
#pragma unroll
      for (int fr = 0; fr < 4; ++fr) {
        acc[fr][cf] = __builtin_amdgcn_mfma_f32_16x16x32_bf16(aH[fr], bH, acc[fr][cf], 0, 0, 0);
        acc[fr][cf] = __builtin_amdgcn_mfma_f32_16x16x32_bf16(aH[fr], bL, acc[fr][cf], 0, 0, 0);
        acc[fr][cf] = __builtin_amdgcn_mfma_f32_16x16x32_bf16(aL[fr], bH, acc[fr][cf], 0, 0, 0);
      }
    }
    __syncthreads();
  }
  // epilogue: D row=(lane>>4)*4+q, col=lane&15 (m89/m91 mapping)
#pragma unroll
  for (int fr = 0; fr < 4; ++fr)
#pragma unroll
    for (int cf = 0; cf < 8; ++cf) {
      int col = cf * 16 + l15;
      float bs = bias[col];
#pragma unroll
      for (int q = 0; q < 4; ++q) {
        size_t row = m0 + wv * 64 + fr * 16 + l4 * 4 + q;
        C[row * ldc + n0 + col] = acc[fr][cf][q] + bs;
      }
    }
#undef LOAD_TILES
}

// --------------------------- pos BiLSTM recurrence ---------------------------
// R7-exact core; outputs pre-split bf16 hi/lo (R14-proven).
__global__ __launch_bounds__(512, 2) void pos_rec(
    const int* __restrict__ lengths, const float* __restrict__ gpos,
    const float* __restrict__ Wf, const float* __restrict__ Wb,
    u16* __restrict__ emh, u16* __restrict__ eml) {
  const int blk = blockIdx.x;
  const int b = blk >> 1, dir = blk & 1;
  const int j = threadIdx.x;
  const int gc = j >> 7;
  const int len = lengths[b];
  const float* W = dir ? Wb : Wf;
  __shared__ __align__(16) float h[128];
  __shared__ float gbuf[512];
  float4 w4[32];
#pragma unroll
  for (int i = 0; i < 32; ++i) w4[i] = *(const float4*)&W[(size_t)j * 128 + i * 4];
#pragma unroll
  for (int i = 0; i < 32; ++i) PIN4(w4[i]);
  float c = 0.f;
  if (j < 128) h[j] = 0.f;
  __syncthreads();
  int idx0 = dir ? (len - 1) : 0;
  float gcur = gpos[((size_t)(b * Tsz + idx0)) * 1024 + dir * 512 + j];
  for (int t = 0; t < len; ++t) {
    const int idx = dir ? (len - 1 - t) : t;
    const int tn = (t + 1 < len) ? t + 1 : t;
    const int idxn = dir ? (len - 1 - tn) : tn;
    float gnext = gpos[((size_t)(b * Tsz + idxn)) * 1024 + dir * 512 + j];
    float acc = gcur;
    const float4* h4 = (const float4*)h;
#pragma unroll
    for (int i = 0; i < 32; ++i) {
      float4 hh = h4[i];
      acc = fmaf(hh.x, w4[i].x, acc); acc = fmaf(hh.y, w4[i].y, acc);
      acc = fmaf(hh.z, w4[i].z, acc); acc = fmaf(hh.w, w4[i].w, acc);
    }
    gbuf[j] = (gc == 2) ? tanhf(acc) : sigm(acc);
    __syncthreads();
    if (j < 128) {
      float si = gbuf[j], sf = gbuf[128 + j], tg = gbuf[256 + j], so = gbuf[384 + j];
      c = sf * c + si * tg;
      float hn = so * tanhf(c);
      h[j] = hn;
      u16 hh2, hl2; bf16split(hn, hh2, hl2);
      size_t eo = ((size_t)(b * Tsz + idx)) * 640 + 384 + dir * 128 + j;
      emh[eo] = hh2; eml[eo] = hl2;
    }
    __syncthreads();
    gcur = gnext;
  }
}

// --------------------------- main BiLSTM recurrence --------------------------
// R7-EXACT core (structural floor: step = 0.7us compute + ~1.7us fabric
// exchange). 256 blocks: blk = b*4 + dir*2 + half; partner = blk^1.
// Weights/thread: 40 f4 PINNED VGPR, 19 f4 LDS, 5 f4 compiler-choice.
// Exchange: packed (tag<<32|bits) relaxed agent atomics, parity dbuf.
// Poll = hard spin (no s_sleep).
#define MR_VF4 40
#define MR_LF4 19
#define MR_TF4 5
#define HX_STRIDE 256      // ull per block (2 parity slots x 128)
__global__ __launch_bounds__(512, 2) void main_rec(
    const int* __restrict__ lengths, const float* __restrict__ gmain,
    const float* __restrict__ Wf, const float* __restrict__ Wb,
    float* __restrict__ lstm_out, unsigned long long* __restrict__ hx) {
  extern __shared__ float smem[];
  float4* wl  = (float4*)smem;                    // [MR_LF4*512] float4
  float* hbuf = smem + MR_LF4 * 512 * 4;          // 256 (full h, absolute idx)
  float* gbuf = hbuf + 256;                       // 512

  const int blk = blockIdx.x;
  const int b = blk >> 2, dir = (blk >> 1) & 1, half = blk & 1;
  const int j = threadIdx.x;
  const int gc = j >> 7, ul = j & 127;
  const int r = gc * 256 + half * 128 + ul;        // gate row in [0,1024)
  const int len = lengths[b];
  const float* Wr = (dir ? Wb : Wf) + (size_t)r * 256;

  float4 wv[MR_VF4];
#pragma unroll
  for (int i = 0; i < MR_VF4; ++i) wv[i] = *(const float4*)&Wr[i * 4];
#pragma unroll
  for (int i = 0; i < MR_VF4; ++i) PIN4(wv[i]);
#pragma unroll
  for (int i = 0; i < MR_LF4; ++i) wl[i * 512 + j] = *(const float4*)&Wr[(MR_VF4 + i) * 4];

  unsigned long long* selfD = hx + (size_t)blk * HX_STRIDE;
  unsigned long long* partD = hx + (size_t)(blk ^ 1) * HX_STRIDE;
  const int obase = dir * 256 + half * 128;

  float c = 0.f;
  if (j < 256) hbuf[j] = 0.f;
  __syncthreads();

  const int idx0 = dir ? (len - 1) : 0;
  float gcur = gmain[((size_t)(b * Tsz + idx0)) * 2048 + dir * 1024 + r];
  for (int t = 0; t < len; ++t) {
    const int idx = dir ? (len - 1 - t) : t;
    const int tn = (t + 1 < len) ? t + 1 : t;
    const int idxn = dir ? (len - 1 - tn) : tn;
    float gnext = gmain[((size_t)(b * Tsz + idxn)) * 2048 + dir * 1024 + r];
    // matvec over full h (t=0: h=0 contributes nothing)
    float acc = gcur;
    const float4* hb4 = (const float4*)hbuf;
#pragma unroll
    for (int i = 0; i < MR_VF4; ++i) {
      float4 hh = hb4[i], w = wv[i];
      acc = fmaf(hh.x, w.x, acc); acc = fmaf(hh.y, w.y, acc);
      acc = fmaf(hh.z, w.z, acc); acc = fmaf(hh.w, w.w, acc);
    }
#pragma unroll
    for (int i = 0; i < MR_LF4; ++i) {
      float4 hh = hb4[MR_VF4 + i], w = wl[i * 512 + j];
      acc = fmaf(hh.x, w.x, acc); acc = fmaf(hh.y, w.y, acc);
      acc = fmaf(hh.z, w.z, acc); acc = fmaf(hh.w, w.w, acc);
    }
#pragma unroll
    for (int i = 0; i < MR_TF4; ++i) {
      float4 hh = hb4[MR_VF4 + MR_LF4 + i];
      float4 w = *(const float4*)&Wr[(MR_VF4 + MR_LF4 + i) * 4];
      acc = fmaf(hh.x, w.x, acc); acc = fmaf(hh.y, w.y, acc);
      acc = fmaf(hh.z, w.z, acc); acc = fmaf(hh.w, w.w, acc);
    }
    gbuf[j] = (gc == 2) ? tanhf(acc) : sigm(acc);
    __syncthreads();
    if (j < 128) {
      float si = gbuf[ul], sf = gbuf[128 + ul], tg = gbuf[256 + ul], so = gbuf[384 + ul];
      c = sf * c + si * tg;
      float hn = so * tanhf(c);
      if (t + 1 < len) {
        union { float f; unsigned u; } cv; cv.f = hn;
        unsigned long long pk =
            ((unsigned long long)(unsigned)(t + 1) << 32) | (unsigned long long)cv.u;
        __hip_atomic_store(&selfD[(t & 1) * 128 + ul], pk,
                           __ATOMIC_RELAXED, __HIP_MEMORY_SCOPE_AGENT);
      }
      lstm_out[((size_t)(b * Tsz + idx)) * 512 + obase + ul] = hn;
      hbuf[half * 128 + ul] = hn;
      if (t + 1 < len) {
        unsigned long long pv; int guard = 0;
        for (;;) {
          pv = __hip_atomic_load(&partD[(t & 1) * 128 + ul],
                                 __ATOMIC_RELAXED, __HIP_MEMORY_SCOPE_AGENT);
          if ((unsigned)(pv >> 32) == (unsigned)(t + 1)) break;
          if (++guard > (1 << 24)) break;   // watchdog (hard spin)
        }
        union { unsigned u; float f; } hv; hv.u = (unsigned)(pv & 0xffffffffull);
        hbuf[(half ^ 1) * 128 + ul] = hv.f;
      }
    }
    __syncthreads();
    gcur = gnext;
  }
}

// ------------------------------- emit GEMM -----------------------------------
__global__ __launch_bounds__(256) void emit_kernel(
    const float* __restrict__ lstm_out, const float* __restrict__ Wout,
    const float* __restrict__ bout, float* __restrict__ emit) {
  int gid = blockIdx.x * 256 + threadIdx.x;      // NROW*32 threads
  int m = gid >> 5, j = gid & 31;
  if (j >= 20) return;
  const float4* xr = (const float4*)&lstm_out[(size_t)m * 512];
  const float4* wr = (const float4*)&Wout[(size_t)j * 512];
  float acc = bout[j];
#pragma unroll 8
  for (int i = 0; i < 128; ++i) {
    float4 x = xr[i], w = wr[i];
    acc += x.x * w.x + x.y * w.y + x.z * w.z + x.w * w.w;
  }
  emit[(size_t)m * 20 + j] = acc;
}

// ------------------------------- Viterbi -------------------------------------
__global__ __launch_bounds__(64) void viterbi_kernel(
    const int* __restrict__ lengths, const float* __restrict__ emit,
    const float* __restrict__ trans, int* __restrict__ out) {
  const int b = blockIdx.x, j = threadIdx.x;
  const int len = lengths[b];
  __shared__ float tr[400];
  __shared__ float alpha[20];
  __shared__ float fin[20];
  __shared__ unsigned char bp[256][20];
  for (int i = j; i < 400; i += 64) tr[i] = trans[i];
  __syncthreads();
  if (j < 20) alpha[j] = tr[18 * 20 + j] + emit[(size_t)(b * Tsz) * 20 + j];
  __syncthreads();
  for (int t = 1; t < len; ++t) {
    float best = 0.f; int bi = 0;
    if (j < 20) {
      best = alpha[0] + tr[j];
#pragma unroll
      for (int i = 1; i < 20; ++i) {
        float s = alpha[i] + tr[i * 20 + j];
        if (s > best) { best = s; bi = i; }
      }
      best += emit[((size_t)(b * Tsz + t)) * 20 + j];
    }
    __syncthreads();
    if (j < 20) { alpha[j] = best; bp[t][j] = (unsigned char)bi; }
    __syncthreads();
  }
  if (j < 20) fin[j] = alpha[j] + tr[j * 20 + 19];
  __syncthreads();
  if (j == 0) {
    float best = fin[0]; int tag = 0;
    for (int i = 1; i < 20; ++i) if (fin[i] > best) { best = fin[i]; tag = i; }
    out[b * Tsz + len - 1] = tag;
    for (int t = len - 1; t >= 1; --t) { tag = bp[t][tag]; out[b * Tsz + t - 1] = tag; }
  }
  for (int t = len + j; t < Tsz; t += 64) out[b * Tsz + t] = 0;
}

// ------------------------------- launcher ------------------------------------
extern "C" void kernel_launch(void* const* d_in, const int* in_sizes, int n_in,
                              void* d_out, int out_size, void* d_ws, size_t ws_size,
                              hipStream_t stream) {
  const int*   char_in = (const int*)d_in[0];
  const int*   pos_in  = (const int*)d_in[1];
  const int*   tag_in  = (const int*)d_in[2];
  const int*   lengths = (const int*)d_in[3];
  // d_in[4] = mask: recomputed from lengths, unused.
  const float* ce      = (const float*)d_in[5];
  const float* pe      = (const float*)d_in[6];
  const float* te      = (const float*)d_in[7];
  const float* pWih_f  = (const float*)d_in[8];
  const float* pWhh_f  = (const float*)d_in[9];
  const float* pb_f    = (const float*)d_in[10];
  const float* pWih_b  = (const float*)d_in[11];
  const float* pWhh_b  = (const float*)d_in[12];
  const float* pb_b    = (const float*)d_in[13];
  const float* mWih_f  = (const float*)d_in[14];
  const float* mWhh_f  = (const float*)d_in[15];
  const float* mb_f    = (const float*)d_in[16];
  const float* mWih_b  = (const float*)d_in[17];
  const float* mWhh_b  = (const float*)d_in[18];
  const float* mb_b    = (const float*)d_in[19];
  const float* W_out   = (const float*)d_in[20];
  const float* b_out   = (const float*)d_in[21];
  const float* trans   = (const float*)d_in[22];

  float* ws = (float*)d_ws;
  // ---- layout (float offsets), overlays verified by stage liveness ----
  const size_t WPH     = 0;                        //  65536 f (131072 u16: pos f|b)
  const size_t WPL     = 65536;                    //  65536
  const size_t WMH     = 131072;                   // 655360 f (main f|b)
  const size_t WML     = 786432;                   // 655360
  const size_t EMH     = 1441792;                  // 5242880 f (16384*640 u16)
  const size_t EML     = 6684672;                  // 5242880
  const size_t TBH     = 11927552;                 // 1048576 f (16384*128 u16)
  const size_t TBL     = 12976128;                 // 1048576
  const size_t GPOS    = 14024704;                 // 16777216 f
  const size_t GMAIN   = 11927552;                 // 33554432 f (overlays TB+GPOS+fresh)
  const size_t LSTMOUT = 1441792;                  // 8388608 f (overlays EMH/EML, dead)
  const size_t EMIT    = 9830400;                  // 327680 f (tail of EM region)
  const size_t HX      = 10158080;                 // 131072 f (low region, pre-GMAIN)

  // prep: gather (8192 blk) + weight pre-split (1408 blk) + HX clear (64 blk)
  prep_kernel<<<9664, 256, 0, stream>>>(
      char_in, pos_in, tag_in, ce, pe, te,
      (u16*)(ws + TBH), (u16*)(ws + TBL), (u16*)(ws + EMH), (u16*)(ws + EML),
      pWih_f, (u16*)(ws + WPH),          (u16*)(ws + WPL),          65536,
      pWih_b, (u16*)(ws + WPH) + 65536,  (u16*)(ws + WPL) + 65536,  65536,
      mWih_f, (u16*)(ws + WMH),          (u16*)(ws + WML),          655360,
      mWih_b, (u16*)(ws + WMH) + 655360, (u16*)(ws + WML) + 655360, 655360,
      (unsigned long long*)(ws + HX));

  const int GSMEM = (2 * 512 * 40 + 2 * 128 * 40) * 2;   // 102400 B
  hipFuncSetAttribute((const void*)gemm_bf16x3,
                      hipFuncAttributeMaxDynamicSharedMemorySize, GSMEM);

  // pos input GEMM (f+b merged): [16384,128] x [1024,128]^T -> GPOS ldc 1024
  gemm_bf16x3<<<dim3(8, 32), 512, GSMEM, stream>>>(
      (u16*)(ws + TBH), (u16*)(ws + TBL),
      (u16*)(ws + WPH), (u16*)(ws + WPL),
      pb_f, pb_b, ws + GPOS, 1024, 128, 4);

  pos_rec<<<128, 512, 0, stream>>>(lengths, ws + GPOS, pWhh_f, pWhh_b,
                                   (u16*)(ws + EMH), (u16*)(ws + EML));

  // main input GEMM (f+b merged): [16384,640] x [2048,640]^T -> GMAIN ldc 2048
  gemm_bf16x3<<<dim3(16, 32), 512, GSMEM, stream>>>(
      (u16*)(ws + EMH), (u16*)(ws + EML),
      (u16*)(ws + WMH), (u16*)(ws + WML),
      mb_f, mb_b, ws + GMAIN, 2048, 640, 8);

  // LDS: 19*512*16 (weights) + 256*4 + 512*4 = 158720 B (<= 160 KiB)
  const int SMEM = MR_LF4 * 512 * 16 + 256 * 4 + 512 * 4;
  hipFuncSetAttribute((const void*)main_rec,
                      hipFuncAttributeMaxDynamicSharedMemorySize, SMEM);
  main_rec<<<256, 512, SMEM, stream>>>(lengths, ws + GMAIN, mWhh_f, mWhh_b,
                                       ws + LSTMOUT, (unsigned long long*)(ws + HX));

  emit_kernel<<<2048, 256, 0, stream>>>(ws + LSTMOUT, W_out, b_out, ws + EMIT);

  viterbi_kernel<<<64, 64, 0, stream>>>(lengths, ws + EMIT, trans, (int*)d_out);
}